// Round 24
// baseline (766.957 us; speedup 1.0000x reference)
//
#include <hip/hip_runtime.h>

// TransformerXL forward, MI355X. Round 24: mems f32->bf16 conversion
// eliminated — gemm_qkv2 mems-path blocks stage A directly from f32 with
// reg-staged convert (ds_write_b128 to the same swizzled address gload16
// used; bitwise-identical values). Removes 100 MB prologue traffic, the
// memsb4 buffer, convk, and big_ws. attn/LN/other GEMMs byte-identical to
// r23 (743 us). L=256, KLEN=512, B=32, E=512, H=8, D=64, FF=2048, NL=4.

typedef __attribute__((ext_vector_type(8))) short bf8_t;    // 8 bf16 in 4 VGPRs
typedef __attribute__((ext_vector_type(4))) float f4_t;
typedef __attribute__((ext_vector_type(16))) float fx16;    // 32x32 accum

__device__ __forceinline__ ushort f2bf(float f) {           // RNE f32->bf16
    uint u = __float_as_uint(f);
    u += 0x7FFFu + ((u >> 16) & 1u);
    return (ushort)(u >> 16);
}
__device__ __forceinline__ float b2f(ushort h) {
    return __uint_as_float(((uint)h) << 16);
}
__device__ __forceinline__ void gload16(const void* g, void* l) {
    __builtin_amdgcn_global_load_lds((const __attribute__((address_space(1))) void*)g,
                                     (__attribute__((address_space(3))) void*)l, 16, 0, 0);
}
// XCD-aware bijective remap (T1): XCD k gets a contiguous chunk of tiles.
__device__ __forceinline__ void xcd_tiles(int& mt, int& nt) {
    const int gx = gridDim.x;
    const int flat = (int)blockIdx.y * gx + (int)blockIdx.x;
    const int q = (gx * gridDim.y) >> 3;
    const int swz = (flat & 7) * q + (flat >> 3);
    nt = swz % gx;
    mt = swz / gx;
}

// ---------------- shared 32x32x16 MFMA core for one BK=64 step -------------
__device__ __forceinline__ void mma32_step(const ushort* __restrict__ As,
                                           const ushort* __restrict__ Bs,
                                           int rowA0, int colB0,
                                           int l31, int hi, fx16 acc[2][2])
{
#pragma unroll
    for (int kk = 0; kk < 4; ++kk) {
        bf8_t av[2], bv[2];
#pragma unroll
        for (int i = 0; i < 2; ++i) {
            const int row = rowA0 + i * 32 + l31;
            const int ch = (kk * 2 + hi) ^ (row & 7);
            av[i] = *(const bf8_t*)(As + row * 64 + ch * 8);
        }
#pragma unroll
        for (int j = 0; j < 2; ++j) {
            const int row = colB0 + j * 32 + l31;
            const int ch = (kk * 2 + hi) ^ (row & 7);
            bv[j] = *(const bf8_t*)(Bs + row * 64 + ch * 8);
        }
#pragma unroll
        for (int i = 0; i < 2; ++i)
#pragma unroll
            for (int j = 0; j < 2; ++j)
                acc[i][j] = __builtin_amdgcn_mfma_f32_32x32x16_bf16(av[i], bv[j], acc[i][j], 0, 0, 0);
    }
}

// ------------------------------------------------------------ MFMA GEMM bf16
template<bool BIAS, bool RELU, bool OUTBF>
__global__ __launch_bounds__(256)
void gemm_bf(const ushort* __restrict__ A, int lda,
             const ushort* __restrict__ Bt, int ldb,
             const float* __restrict__ bias,
             void* __restrict__ Cp, int ldc,
             int M, int N, int K)
{
    __shared__ __align__(16) ushort sh[17408];   // staging 32KB / epi [128][136]
    ushort* As = sh;
    ushort* Bs = sh + 8192;
    const int t = threadIdx.x;
    const int w = t >> 6, lane = t & 63;
    const int wr = w >> 1, wc = w & 1;
    const int l31 = lane & 31, hi = lane >> 5;
    int mt, nt; xcd_tiles(mt, nt);
    const int m0 = mt * 128, n0 = nt * 128;

    const int srow = w * 8 + (lane >> 3);
    const int gchunk = (lane & 7) ^ (srow & 7);
    const ushort* Ag = A + (size_t)(m0 + srow) * lda + gchunk * 8;
    const ushort* Bg = Bt + (size_t)(n0 + srow) * ldb + gchunk * 8;
    ushort* Asw = As + w * 512;
    ushort* Bsw = Bs + w * 512;

    fx16 acc[2][2];
#pragma unroll
    for (int i = 0; i < 2; ++i)
#pragma unroll
        for (int j = 0; j < 2; ++j)
#pragma unroll
            for (int r = 0; r < 16; ++r) acc[i][j][r] = 0.f;

    for (int k0 = 0; k0 < K; k0 += 64) {
#pragma unroll
        for (int c = 0; c < 4; ++c) {
            gload16(Ag + (size_t)c * 32 * lda, Asw + c * 2048);
            gload16(Bg + (size_t)c * 32 * ldb, Bsw + c * 2048);
        }
        Ag += 64; Bg += 64;
        __syncthreads();
        mma32_step(As, Bs, wr * 64, wc * 64, l31, hi, acc);
        __syncthreads();
    }
    const int crow0 = wr * 64, ccol0 = wc * 64;
    if (OUTBF) {
        ushort* Cs = sh;   // [128][136]
#pragma unroll
        for (int i = 0; i < 2; ++i)
#pragma unroll
            for (int j = 0; j < 2; ++j) {
                const int colb = ccol0 + j * 32 + l31;
                float bb = BIAS ? bias[n0 + colb] : 0.f;
                fx16 v = acc[i][j];
#pragma unroll
                for (int r = 0; r < 16; ++r) {
                    float o = v[r] + bb;
                    if (RELU) o = fmaxf(o, 0.f);
                    const int rw = crow0 + i * 32 + (r & 3) + 8 * (r >> 2) + 4 * hi;
                    Cs[rw * 136 + colb] = f2bf(o);
                }
            }
        __syncthreads();
        const int orow = t >> 1, oc0 = (t & 1) * 64;
        ushort* dst = (ushort*)Cp + (size_t)(m0 + orow) * ldc + n0 + oc0;
#pragma unroll
        for (int u = 0; u < 8; ++u)
            *(bf8_t*)(dst + u * 8) = *(const bf8_t*)(Cs + orow * 136 + oc0 + u * 8);
    } else {
        float* C = (float*)Cp;
#pragma unroll
        for (int i = 0; i < 2; ++i)
#pragma unroll
            for (int j = 0; j < 2; ++j) {
                const int colb = n0 + ccol0 + j * 32 + l31;
                float bb = BIAS ? bias[colb] : 0.f;
                fx16 v = acc[i][j];
#pragma unroll
                for (int r = 0; r < 16; ++r) {
                    float o = v[r] + bb;
                    if (RELU) o = fmaxf(o, 0.f);
                    const int rw = crow0 + i * 32 + (r & 3) + 8 * (r >> 2) + 4 * hi;
                    C[(size_t)(m0 + rw) * ldc + colb] = o;
                }
            }
    }
}

// --------- merged q|kv(cur) + kv(mems) GEMM (+layer-0: r = pos_emb @ Wr) ---
// grid (20,64) for l>0; (21,64) for l==0 where nt==20 routes the 64 r4 tiles.
// mems-path (nt in [12,20)) stages A DIRECTLY from f32 mems: reg-load two
// float4, RNE-convert, ds_write_b128 to the exact LDS address gload16 would
// target (Asw + c*2048 + lane*8, source pre-swizzled by gchunk) — bitwise-
// identical staging content to the old pre-converted bf16 buffer.
__global__ __launch_bounds__(256)
void gemm_qkv2(const ushort* __restrict__ Acur, const float* __restrict__ Amemf,
               const ushort* __restrict__ wqkvT_l,
               ushort* __restrict__ qout, ushort* __restrict__ kvout,
               const ushort* __restrict__ peA, const ushort* __restrict__ wrTall,
               ushort* __restrict__ r4out)
{
    __shared__ __align__(16) ushort sh[17408];
    ushort* As = sh;
    ushort* Bs = sh + 8192;
    const int t = threadIdx.x;
    const int w = t >> 6, lane = t & 63;
    const int wr = w >> 1, wc = w & 1;
    const int l31 = lane & 31, hi = lane >> 5;
    int mt, nt; xcd_tiles(mt, nt);

    int m0;
    const ushort* A = nullptr;
    const float*  Af = nullptr;
    const ushort* Bt;
    ushort* base; size_t ldc2;
    if (nt >= 20) {          // layer-0 extra column: r = pos_emb @ Wr[z]
        const int rid = mt;  // 0..63
        const int rz = rid >> 4, rm = (rid >> 2) & 3, rn = rid & 3;
        m0 = rm * 128;
        A = peA;
        Bt = wrTall + (size_t)rz * 262144 + (size_t)(rn * 128) * 512;
        base = r4out + (size_t)rz * 262144 + rn * 128;
        ldc2 = 512;
    } else if (nt < 12) {
        const int n0 = nt * 128;
        m0 = mt * 128;
        A = Acur;
        Bt = wqkvT_l + (size_t)n0 * 512;
        if (n0 < 512) { base = qout + n0; ldc2 = 512; }
        else          { base = kvout + (size_t)8192 * 1024 + (n0 - 512); ldc2 = 1024; }
    } else {
        const int n0 = (nt - 12) * 128;
        m0 = mt * 128;
        Af = Amemf;          // direct f32 mems
        Bt = wqkvT_l + (size_t)(512 + n0) * 512;
        base = kvout + n0; ldc2 = 1024;
    }

    const int srow = w * 8 + (lane >> 3);
    const int gchunk = (lane & 7) ^ (srow & 7);
    const ushort* Ag  = A  ? A  + (size_t)(m0 + srow) * 512 + gchunk * 8 : nullptr;
    const float*  Afg = Af ? Af + (size_t)(m0 + srow) * 512 + gchunk * 8 : nullptr;
    const ushort* Bg = Bt + (size_t)srow * 512 + gchunk * 8;
    ushort* Asw = As + w * 512;
    ushort* Bsw = Bs + w * 512;

    fx16 acc[2][2];
#pragma unroll
    for (int i = 0; i < 2; ++i)
#pragma unroll
        for (int j = 0; j < 2; ++j)
#pragma unroll
            for (int r = 0; r < 16; ++r) acc[i][j][r] = 0.f;

    for (int k0 = 0; k0 < 512; k0 += 64) {
        if (Af) {
#pragma unroll
            for (int c = 0; c < 4; ++c) {
                gload16(Bg + (size_t)c * 32 * 512, Bsw + c * 2048);
                float4 v0 = *(const float4*)(Afg + (size_t)c * 32 * 512);
                float4 v1 = *(const float4*)(Afg + (size_t)c * 32 * 512 + 4);
                bf8_t o8;
                o8[0] = (short)f2bf(v0.x); o8[1] = (short)f2bf(v0.y);
                o8[2] = (short)f2bf(v0.z); o8[3] = (short)f2bf(v0.w);
                o8[4] = (short)f2bf(v1.x); o8[5] = (short)f2bf(v1.y);
                o8[6] = (short)f2bf(v1.z); o8[7] = (short)f2bf(v1.w);
                *(bf8_t*)(Asw + c * 2048 + lane * 8) = o8;
            }
            Afg += 64;
        } else {
#pragma unroll
            for (int c = 0; c < 4; ++c) {
                gload16(Ag + (size_t)c * 32 * 512, Asw + c * 2048);
                gload16(Bg + (size_t)c * 32 * 512, Bsw + c * 2048);
            }
            Ag += 64;
        }
        Bg += 64;
        __syncthreads();
        mma32_step(As, Bs, wr * 64, wc * 64, l31, hi, acc);
        __syncthreads();
    }
    const int crow0 = wr * 64, ccol0 = wc * 64;
    ushort* Cs = sh;   // [128][136]
#pragma unroll
    for (int i = 0; i < 2; ++i)
#pragma unroll
        for (int j = 0; j < 2; ++j) {
            const int colb = ccol0 + j * 32 + l31;
            fx16 v = acc[i][j];
#pragma unroll
            for (int r = 0; r < 16; ++r) {
                const int rw = crow0 + i * 32 + (r & 3) + 8 * (r >> 2) + 4 * hi;
                Cs[rw * 136 + colb] = f2bf(v[r]);
            }
        }
    __syncthreads();
    const int orow = t >> 1, oc0 = (t & 1) * 64;
    ushort* dst = base + (size_t)(m0 + orow) * ldc2 + oc0;
#pragma unroll
    for (int u = 0; u < 8; ++u)
        *(bf8_t*)(dst + u * 8) = *(const bf8_t*)(Cs + orow * 136 + oc0 + u * 8);
}

// ------------------------------------------------ split-K GEMM (f32 partials)
template<bool BIAS>
__global__ __launch_bounds__(256)
void gemm_sk(const ushort* __restrict__ A, int lda,
             const ushort* __restrict__ Bt, int ldb,
             const float* __restrict__ bias,
             float* __restrict__ C0, float* __restrict__ C1, int ldc, int KH)
{
    __shared__ __align__(16) ushort sh[16384];
    ushort* As = sh;
    ushort* Bs = sh + 8192;
    const int t = threadIdx.x;
    const int w = t >> 6, lane = t & 63;
    const int wr = w >> 1, wc = w & 1;
    const int l31 = lane & 31, hi = lane >> 5;
    int mt, nt; xcd_tiles(mt, nt);
    const int m0 = mt * 128, n0 = nt * 128;
    const int z = blockIdx.z;
    A += (size_t)z * KH; Bt += (size_t)z * KH;
    float* C = z ? C1 : C0;

    const int srow = w * 8 + (lane >> 3);
    const int gchunk = (lane & 7) ^ (srow & 7);
    const ushort* Ag = A + (size_t)(m0 + srow) * lda + gchunk * 8;
    const ushort* Bg = Bt + (size_t)(n0 + srow) * ldb + gchunk * 8;
    ushort* Asw = As + w * 512;
    ushort* Bsw = Bs + w * 512;

    fx16 acc[2][2];
#pragma unroll
    for (int i = 0; i < 2; ++i)
#pragma unroll
        for (int j = 0; j < 2; ++j)
#pragma unroll
            for (int r = 0; r < 16; ++r) acc[i][j][r] = 0.f;

    for (int k0 = 0; k0 < KH; k0 += 64) {
#pragma unroll
        for (int c = 0; c < 4; ++c) {
            gload16(Ag + (size_t)c * 32 * lda, Asw + c * 2048);
            gload16(Bg + (size_t)c * 32 * ldb, Bsw + c * 2048);
        }
        Ag += 64; Bg += 64;
        __syncthreads();
        mma32_step(As, Bs, wr * 64, wc * 64, l31, hi, acc);
        __syncthreads();
    }
    const int crow0 = wr * 64, ccol0 = wc * 64;
#pragma unroll
    for (int i = 0; i < 2; ++i)
#pragma unroll
        for (int j = 0; j < 2; ++j) {
            const int colb = n0 + ccol0 + j * 32 + l31;
            float bb = (BIAS && z == 0) ? bias[colb] : 0.f;
            fx16 v = acc[i][j];
#pragma unroll
            for (int r = 0; r < 16; ++r) {
                const int rw = crow0 + i * 32 + (r & 3) + 8 * (r >> 2) + 4 * hi;
                C[(size_t)(m0 + rw) * ldc + colb] = v[r] + bb;
            }
        }
}

// ---------------------------------------------------------------- LayerNorm
// RMODE: 0 X; 3 X+X2+Rbf16. TROUT: f32 out transposed to [B,L].
template<int RMODE, bool TROUT>
__global__ __launch_bounds__(256)
void ln_k(const float* __restrict__ X, const float* __restrict__ X2,
          const void* __restrict__ Rp,
          const float* __restrict__ g, const float* __restrict__ bt,
          float* __restrict__ Yf, ushort* __restrict__ Yb,
          float eps, int do_relu)
{
    const int row  = blockIdx.x * 4 + (threadIdx.x >> 6);
    const int lane = threadIdx.x & 63;
    const float* xp = X + (size_t)row * 512 + lane * 8;
    float4 x0 = *(const float4*)xp, x1 = *(const float4*)(xp + 4);
    float v[8] = {x0.x, x0.y, x0.z, x0.w, x1.x, x1.y, x1.z, x1.w};
    if (RMODE == 3) {
        const float* p2 = X2 + (size_t)row * 512 + lane * 8;
        float4 a0 = *(const float4*)p2, a1 = *(const float4*)(p2 + 4);
        v[0] += a0.x; v[1] += a0.y; v[2] += a0.z; v[3] += a0.w;
        v[4] += a1.x; v[5] += a1.y; v[6] += a1.z; v[7] += a1.w;
        const ushort* rp = (const ushort*)Rp + (size_t)row * 512 + lane * 8;
        ushort4 r0 = *(const ushort4*)rp, r1 = *(const ushort4*)(rp + 4);
        v[0] += b2f(r0.x); v[1] += b2f(r0.y); v[2] += b2f(r0.z); v[3] += b2f(r0.w);
        v[4] += b2f(r1.x); v[5] += b2f(r1.y); v[6] += b2f(r1.z); v[7] += b2f(r1.w);
    }
    float s = 0.f;
#pragma unroll
    for (int i = 0; i < 8; ++i) s += v[i];
#pragma unroll
    for (int m = 1; m < 64; m <<= 1) s += __shfl_xor(s, m);
    float mean = s * (1.f / 512.f);
    float q = 0.f;
#pragma unroll
    for (int i = 0; i < 8; ++i) { float d = v[i] - mean; q = fmaf(d, d, q); }
#pragma unroll
    for (int m = 1; m < 64; m <<= 1) q += __shfl_xor(q, m);
    float rstd = rsqrtf(q * (1.f / 512.f) + eps);
    float4 g0 = *(const float4*)(g + lane * 8), g1 = *(const float4*)(g + lane * 8 + 4);
    float4 c0 = *(const float4*)(bt + lane * 8), c1 = *(const float4*)(bt + lane * 8 + 4);
    float gv[8] = {g0.x, g0.y, g0.z, g0.w, g1.x, g1.y, g1.z, g1.w};
    float bv[8] = {c0.x, c0.y, c0.z, c0.w, c1.x, c1.y, c1.z, c1.w};
    float o[8];
#pragma unroll
    for (int i = 0; i < 8; ++i) {
        o[i] = (v[i] - mean) * rstd * gv[i] + bv[i];
        if (do_relu) o[i] = fmaxf(o[i], 0.f);
    }
    if (Yf) {
        float* yp;
        if (TROUT) {
            const int bq = row & 31, lq = row >> 5;
            yp = Yf + ((size_t)bq * 256 + lq) * 512 + lane * 8;
        } else {
            yp = Yf + (size_t)row * 512 + lane * 8;
        }
        *(float4*)yp       = make_float4(o[0], o[1], o[2], o[3]);
        *(float4*)(yp + 4) = make_float4(o[4], o[5], o[6], o[7]);
    }
    if (Yb) {
        ushort* yp = Yb + (size_t)row * 512 + lane * 8;
        ushort4 w0, w1;
        w0.x = f2bf(o[0]); w0.y = f2bf(o[1]); w0.z = f2bf(o[2]); w0.w = f2bf(o[3]);
        w1.x = f2bf(o[4]); w1.y = f2bf(o[5]); w1.z = f2bf(o[6]); w1.w = f2bf(o[7]);
        *(ushort4*)yp       = w0;
        *(ushort4*)(yp + 4) = w1;
    }
}

// ------------------ fused stem double LN (ln2 -> lnf), X = X1 + X2 partials
__global__ __launch_bounds__(256)
void ln_stem2(const float* __restrict__ X, const float* __restrict__ X2,
              const float* __restrict__ g1, const float* __restrict__ b1,
              const float* __restrict__ g2, const float* __restrict__ b2,
              ushort* __restrict__ Yb)
{
    const int row  = blockIdx.x * 4 + (threadIdx.x >> 6);
    const int lane = threadIdx.x & 63;
    const float* xp = X + (size_t)row * 512 + lane * 8;
    const float* ap = X2 + (size_t)row * 512 + lane * 8;
    float4 x0 = *(const float4*)xp, x1 = *(const float4*)(xp + 4);
    float4 a0 = *(const float4*)ap, a1 = *(const float4*)(ap + 4);
    float v[8] = {x0.x + a0.x, x0.y + a0.y, x0.z + a0.z, x0.w + a0.w,
                  x1.x + a1.x, x1.y + a1.y, x1.z + a1.z, x1.w + a1.w};
    float s = 0.f;
#pragma unroll
    for (int i = 0; i < 8; ++i) s += v[i];
#pragma unroll
    for (int m = 1; m < 64; m <<= 1) s += __shfl_xor(s, m);
    float mean = s * (1.f / 512.f);
    float q = 0.f;
#pragma unroll
    for (int i = 0; i < 8; ++i) { float d = v[i] - mean; q = fmaf(d, d, q); }
#pragma unroll
    for (int m = 1; m < 64; m <<= 1) q += __shfl_xor(q, m);
    float rstd = rsqrtf(q * (1.f / 512.f) + 1e-5f);
#pragma unroll
    for (int i = 0; i < 8; ++i)
        v[i] = (v[i] - mean) * rstd * g1[lane * 8 + i] + b1[lane * 8 + i];
    s = 0.f;
#pragma unroll
    for (int i = 0; i < 8; ++i) s += v[i];
#pragma unroll
    for (int m = 1; m < 64; m <<= 1) s += __shfl_xor(s, m);
    mean = s * (1.f / 512.f);
    q = 0.f;
#pragma unroll
    for (int i = 0; i < 8; ++i) { float d = v[i] - mean; q = fmaf(d, d, q); }
#pragma unroll
    for (int m = 1; m < 64; m <<= 1) q += __shfl_xor(q, m);
    rstd = rsqrtf(q * (1.f / 512.f) + 1e-6f);
    float o[8];
#pragma unroll
    for (int i = 0; i < 8; ++i)
        o[i] = (v[i] - mean) * rstd * g2[lane * 8 + i] + b2[lane * 8 + i];
    ushort* yb = Yb + (size_t)row * 512 + lane * 8;
    ushort4 w0, w1;
    w0.x = f2bf(o[0]); w0.y = f2bf(o[1]); w0.z = f2bf(o[2]); w0.w = f2bf(o[3]);
    w1.x = f2bf(o[4]); w1.y = f2bf(o[5]); w1.z = f2bf(o[6]); w1.w = f2bf(o[7]);
    *(ushort4*)yb       = w0;
    *(ushort4*)(yb + 4) = w1;
}

// ---------------- merged prologue: posemb + xcat + all weight transposes ---
// Flat grid routing: [128 posemb] [2304 xcat] [3464 wt]. No mems conversion
// (qkv2 stages mems f32 directly now).
__global__ __launch_bounds__(256)
void wtrans_all(const float* __restrict__ sw1, const float* __restrict__ sw2,
                const float* __restrict__ Wqkv, const float* __restrict__ Wr,
                const float* __restrict__ Wo, const float* __restrict__ W1w,
                const float* __restrict__ W2w,
                ushort* __restrict__ w1t, ushort* __restrict__ w2t,
                ushort* __restrict__ wqkvT, ushort* __restrict__ wrT,
                ushort* __restrict__ woT, ushort* __restrict__ w1T,
                ushort* __restrict__ w2T,
                ushort* __restrict__ pe,
                const float* __restrict__ x, const int* __restrict__ action,
                const float* __restrict__ act_emb, ushort* __restrict__ xcat)
{
    int id = (int)blockIdx.x;
    if (id < 128) {         // sinusoidal pos embedding, 8 c/thread
        int v = id * 256 + threadIdx.x;            // 32768 threads
        int j = v >> 6, c0 = (v & 63) * 8;
        float pf = (float)(511 - j);
        bf8_t o8;
#pragma unroll
        for (int e = 0; e < 8; ++e) {
            int c = c0 + e;
            int i2 = (c < 256) ? c : c - 256;
            float inv = expf(-(float)i2 * 0.03597789207803197f);
            float ang = pf * inv;
            o8[e] = (short)f2bf((c < 256) ? sinf(ang) : cosf(ang));
        }
        *(bf8_t*)(pe + (size_t)j * 512 + c0) = o8;
        return;
    }
    id -= 128;
    if (id < 2304) {        // stem concat [x | act], 8 e/thread
        int v = id * 256 + threadIdx.x;            // 8192*72 groups
        int n = v / 72, eg = v - n * 72;
        int e0 = eg * 8;
        int l = n >> 5, b = n & 31;
        float4 v0, v1;
        if (e0 < 512) {
            const float* src = x + ((size_t)b * 256 + l) * 512 + e0;
            v0 = *(const float4*)src;
            v1 = *(const float4*)(src + 4);
        } else {
            const float* src = act_emb + (size_t)action[b * 32 + (l >> 3)] * 64 + (e0 - 512);
            v0 = *(const float4*)src;
            v1 = *(const float4*)(src + 4);
        }
        bf8_t o8;
        o8[0] = (short)f2bf(v0.x); o8[1] = (short)f2bf(v0.y);
        o8[2] = (short)f2bf(v0.z); o8[3] = (short)f2bf(v0.w);
        o8[4] = (short)f2bf(v1.x); o8[5] = (short)f2bf(v1.y);
        o8[6] = (short)f2bf(v1.z); o8[7] = (short)f2bf(v1.w);
        *(bf8_t*)(xcat + (size_t)n * 576 + e0) = o8;
        return;
    }
    id -= 2304;
    // ---- 64x64 transpose tiles ----
    const float* in; ushort* out; int K, N, nx, bz = 0;
    if (id < 72) { in = sw1; out = w1t; K = 576; N = 512; nx = 8; }
    else if ((id -= 72) < 64) { in = sw2; out = w2t; K = 512; N = 512; nx = 8; }
    else if ((id -= 64) < 768) { in = Wqkv; out = wqkvT; K = 512; N = 1536; nx = 24; bz = id / 192; id -= bz * 192; }
    else if ((id -= 768) < 256) { in = Wr; out = wrT; K = 512; N = 512; nx = 8; bz = id / 64; id -= bz * 64; }
    else if ((id -= 256) < 256) { in = Wo; out = woT; K = 512; N = 512; nx = 8; bz = id / 64; id -= bz * 64; }
    else if ((id -= 256) < 1024) { in = W1w; out = w1T; K = 512; N = 2048; nx = 32; bz = id / 256; id -= bz * 256; }
    else { id -= 1024; in = W2w; out = w2T; K = 2048; N = 512; nx = 8; bz = id / 256; id -= bz * 256; }
    const int bx = id % nx, by = id / nx;
    __shared__ float tl[64][65];
    const size_t bo = (size_t)bz * K * N;
    const float* inp = in + bo;
    ushort* outp = out + bo;
    const int k0 = by * 64, n0 = bx * 64;
    const int tx4 = (threadIdx.x & 15) * 4, ty = threadIdx.x >> 4;   // 16x16
#pragma unroll
    for (int p2 = 0; p2 < 4; ++p2) {
        const int row = p2 * 16 + ty;
        float4 v = *(const float4*)(inp + (size_t)(k0 + row) * N + n0 + tx4);
        tl[row][tx4] = v.x; tl[row][tx4 + 1] = v.y;
        tl[row][tx4 + 2] = v.z; tl[row][tx4 + 3] = v.w;
    }
    __syncthreads();
    const int nn = threadIdx.x >> 3, kk = (threadIdx.x & 7) * 8;     // 32 n/pass
#pragma unroll
    for (int p2 = 0; p2 < 2; ++p2) {
        const int n = p2 * 32 + nn;
        bf8_t o8;
#pragma unroll
        for (int e = 0; e < 8; ++e) o8[e] = (short)f2bf(tl[kk + e][n]);
        *(bf8_t*)(outp + (size_t)(n0 + n) * K + k0 + kk) = o8;
    }
}

// --------------------------------------------------- MFMA flash attention
// r23 kernel: XCD remap, Vs XOR-swizzle, Rs rolling band, T14 prefetch,
// T5 setprio, T13 defer-max, deferred softmax-sum + deferred max-reduce.
__global__ __launch_bounds__(512)
void attn_mfma(const ushort* __restrict__ q,    // [256*32][512]
               const ushort* __restrict__ kv,   // [512*32][1024]  k | v halves
               const ushort* __restrict__ rb,   // [512][512]
               const float* __restrict__ ub, const float* __restrict__ vb,
               ushort* __restrict__ ao)         // [256*32][512]
{
    __shared__ __align__(16) ushort Ks[64][72];     // K tile  [j][d]
    __shared__ __align__(16) ushort Vs[64][72];     // V^T tile [d][j], XOR-swz
    __shared__ __align__(16) ushort Rs[192][72];    // rolling r band (3 slabs)
    __shared__ __align__(16) ushort Ps[8][16][72];  // per-wave P / O bounce
    const int t = threadIdx.x;
    const int wv = t >> 6, lane = t & 63;
    const int lc = lane & 15, lr = lane >> 4;
    const int p = (int)blockIdx.x;
    const int b = (p & 7) * 4 + (p >> 7);
    const int hi2 = (p >> 3) & 15;
    const int h = hi2 >> 1, ihalf = hi2 & 1;
    const int i0 = ihalf << 7;
    const int iw = i0 + wv * 16;

    bf8_t au[2], aw[2];
#pragma unroll
    for (int kk = 0; kk < 2; ++kk) {
        const ushort* qp = q + ((size_t)(iw + lc) * 32 + b) * 512 + h * 64 + kk * 32 + lr * 8;
        bf8_t q8 = *(const bf8_t*)qp;
        const float* up = ub + h * 64 + kk * 32 + lr * 8;
        const float* vp = vb + h * 64 + kk * 32 + lr * 8;
#pragma unroll
        for (int e = 0; e < 8; ++e) {
            float qf = b2f((ushort)q8[e]);
            au[kk][e] = (short)f2bf(qf + up[e]);
            aw[kk][e] = (short)f2bf(qf + vp[e]);
        }
    }

    const int jl = t >> 3, d0 = (t & 7) * 8;
    const int vrow = ((t >> 3) & 7) * 8 + wv;
    const int vswz = ((((vrow >> 3) ^ (t & 7)) & 7) << 3) + (vrow & 7);

    f4_t o[4];
#pragma unroll
    for (int d = 0; d < 4; ++d) o[d] = (f4_t){0.f, 0.f, 0.f, 0.f};
    float mrun[4] = {-3.0e38f, -3.0e38f, -3.0e38f, -3.0e38f};
    float lrun[4] = {0.f, 0.f, 0.f, 0.f};   // per-lane PARTIAL (4 cols/lane)

    {
        *(bf8_t*)&Ks[jl][d0] = *(const bf8_t*)(kv + ((size_t)jl * 32 + b) * 1024 + h * 64 + d0);
        bf8_t vv = *(const bf8_t*)(kv + ((size_t)vrow * 32 + b) * 1024 + 512 + h * 64 + d0);
#pragma unroll
        for (int e = 0; e < 8; ++e) Vs[d0 + e][vswz] = (ushort)vv[e];
        const int rbase0 = 128 - i0;
#pragma unroll
        for (int p2 = 0; p2 < 3; ++p2) {
            const int jr = min(rbase0 + p2 * 64 + jl, 511);
            *(bf8_t*)&Rs[p2 * 64 + jl][d0] = *(const bf8_t*)(rb + (size_t)jr * 512 + h * 64 + d0);
        }
    }
    __syncthreads();

    const int njt = ihalf ? 8 : 6;
    for (int jt = 0; jt < njt; ++jt) {
        const int j0 = jt << 6;
        bf8_t pk, pv, pr;
        const bool pfq = (jt + 1 < njt);
        if (pfq) {
            const int j0n = j0 + 64;
            pk = *(const bf8_t*)(kv + ((size_t)(j0n + jl) * 32 + b) * 1024 + h * 64 + d0);
            pv = *(const bf8_t*)(kv + ((size_t)(j0n + vrow) * 32 + b) * 1024 + 512 + h * 64 + d0);
            const int jr = min(j0n - i0 + 256 + jl, 511);
            pr = *(const bf8_t*)(rb + (size_t)jr * 512 + h * 64 + d0);
        }
        if (j0 <= iw + 271) {
            f4_t acf[4], bdf[5];
#pragma unroll
            for (int jj = 0; jj < 4; ++jj) acf[jj] = (f4_t){0.f, 0.f, 0.f, 0.f};
#pragma unroll
            for (int fj = 0; fj < 5; ++fj) bdf[fj] = (f4_t){0.f, 0.f, 0.f, 0.f};
            __builtin_amdgcn_s_setprio(1);
#pragma unroll
            for (int jj = 0; jj < 4; ++jj)
#pragma unroll
                for (int kk = 0; kk < 2; ++kk) {
                    bf8_t kf = *(const bf8_t*)&Ks[jj * 16 + lc][kk * 32 + lr * 8];
                    acf[jj] = __builtin_amdgcn_mfma_f32_16x16x32_bf16(au[kk], kf, acf[jj], 0, 0, 0);
                }
            const int rboff = 112 - wv * 16;
#pragma unroll
            for (int fj = 0; fj < 5; ++fj) {
                const int lbase = rboff + fj * 16;
                const int prow = ((jt + (lbase >> 6)) % 3) * 64 + (lbase & 63) + lc;
#pragma unroll
                for (int kk = 0; kk < 2; ++kk) {
                    bf8_t rf = *(const bf8_t*)&Rs[prow][kk * 32 + lr * 8];
                    bdf[fj] = __builtin_amdgcn_mfma_f32_16x16x32_bf16(aw[kk], rf, bdf[fj], 0, 0, 0);
                }
            }
            __builtin_amdgcn_s_setprio(0);
            float pm[4][4];
            float mt2[4] = {-3.0e38f, -3.0e38f, -3.0e38f, -3.0e38f};
            const int jbase = j0 + lc - iw - 256;
#pragma unroll
            for (int rg = 0; rg < 4; ++rg) {
                const int il = lr * 4 + rg;
                const int srcl = (lane & 48) | ((lc + 15 - il) & 15);
                float shf[5];
#pragma unroll
                for (int fj = 0; fj < 5; ++fj) shf[fj] = __shfl(bdf[fj][rg], srcl, 64);
#pragma unroll
                for (int jj = 0; jj < 4; ++jj) {
                    float bd = (lc > il) ? shf[jj + 1] : shf[jj];
                    float s = (acf[jj][rg] + bd) * 0.125f;
                    if (jbase + jj * 16 > il) s = -1e30f;
                    pm[jj][rg] = s;
                    mt2[rg] = fmaxf(mt2[rg], s);
                }
            }
            // deferred max-reduce: per-lane partial check first; the 16-lane
            // reduce runs only when a rescale actually triggers (rare).
            const bool within = (mt2[0] <= mrun[0] + 8.f) & (mt2[1] <= mrun[1] + 8.f) &
                                (mt2[2] <= mrun[2] + 8.f) & (mt2[3] <= mrun[3] + 8.f);
            const bool skip_rescale = __all(within);
            float corr[4] = {1.f, 1.f, 1.f, 1.f};
            if (!skip_rescale) {
#pragma unroll
                for (int rg = 0; rg < 4; ++rg) {
#pragma unroll
                    for (int mm = 1; mm < 16; mm <<= 1)
                        mt2[rg] = fmaxf(mt2[rg], __shfl_xor(mt2[rg], mm, 64));
                    float mnew = fmaxf(mrun[rg], mt2[rg]);
                    corr[rg] = __expf(mrun[rg] - mnew);
                    mrun[rg] = mnew;
                }
            }
            float ps4[4] = {0.f, 0.f, 0.f, 0.f};
#pragma unroll
            for (int jj = 0; jj < 4; ++jj)
#pragma unroll
                for (int rg = 0; rg < 4; ++rg) {
                    float pp = __expf(pm[jj][rg] - mrun[rg]);
                    ps4[rg] += pp;
                    Ps[wv][lr * 4 + rg][jj * 16 + lc] = f2bf(pp);
                }
            // deferred: lrun stays a per-lane partial (corr is lane-uniform)
#pragma unroll
            for (int rg = 0; rg < 4; ++rg)
                lrun[rg] = lrun[rg] * corr[rg] + ps4[rg];
            if (!skip_rescale) {
                float c0 = __shfl(corr[0], (lc >> 2) << 4, 64);
                float c1 = __shfl(corr[1], (lc >> 2) << 4, 64);
                float c2 = __shfl(corr[2], (lc >> 2) << 4, 64);
                float c3 = __shfl(corr[3], (lc >> 2) << 4, 64);
                float myc = (lc & 2) ? ((lc & 1) ? c3 : c2) : ((lc & 1) ? c1 : c0);
#pragma unroll
                for (int db = 0; db < 4; ++db)
#pragma unroll
                    for (int rg = 0; rg < 4; ++rg) o[db][rg] *= myc;
            }
            __builtin_amdgcn_s_setprio(1);
#pragma unroll
            for (int kb = 0; kb < 2; ++kb) {
                bf8_t pf = *(const bf8_t*)&Ps[wv][lc][kb * 32 + lr * 8];
#pragma unroll
                for (int db = 0; db < 4; ++db) {
                    const int vr = db * 16 + lc;
                    bf8_t vf = *(const bf8_t*)&Vs[vr][((kb * 4 + lr) ^ ((vr >> 3) & 7)) * 8];
                    o[db] = __builtin_amdgcn_mfma_f32_16x16x32_bf16(vf, pf, o[db], 0, 0, 0);
                }
            }
            __builtin_amdgcn_s_setprio(0);
        }
        __syncthreads();
        if (pfq) {
            *(bf8_t*)&Ks[jl][d0] = pk;
#pragma unroll
            for (int e = 0; e < 8; ++e) Vs[d0 + e][vswz] = (ushort)pv[e];
            const int phys = (jt % 3) * 64 + jl;
            *(bf8_t*)&Rs[phys][d0] = pr;
        }
        __syncthreads();
    }
    // ---- epilogue: single 16-lane sum reduce, then scale + store ----
    float i4[4];
#pragma unroll
    for (int rg = 0; rg < 4; ++rg) {
#pragma unroll
        for (int mm = 1; mm < 16; mm <<= 1)
            lrun[rg] += __shfl_xor(lrun[rg], mm, 64);
        i4[rg] = 1.f / lrun[rg];
    }
    float s0 = __shfl(i4[0], (lc >> 2) << 4, 64);
    float s1 = __shfl(i4[1], (lc >> 2) << 4, 64);
    float s2 = __shfl(i4[2], (lc >> 2) << 4, 64);
    float s3 = __shfl(i4[3], (lc >> 2) << 4, 64);
    float myi = (lc & 2) ? ((lc & 1) ? s3 : s2) : ((lc & 1) ? s1 : s0);
#pragma unroll
    for (int db = 0; db < 4; ++db)
#pragma unroll
        for (int rg = 0; rg < 4; ++rg)
            Ps[wv][lc][db * 16 + lr * 4 + rg] = f2bf(o[db][rg] * myi);
    const int il2 = lane >> 2, dsg = (lane & 3) << 4;
    bf8_t e0 = *(const bf8_t*)&Ps[wv][il2][dsg];
    bf8_t e1 = *(const bf8_t*)&Ps[wv][il2][dsg + 8];
    ushort* dst = ao + ((size_t)(iw + il2) * 32 + b) * 512 + h * 64 + dsg;
    *(bf8_t*)dst = e0;
    *(bf8_t*)(dst + 8) = e1;
}

// ---------------------------------------------------------------------------
extern "C" void kernel_launch(void* const* d_in, const int* in_sizes, int n_in,
                              void* d_out, int out_size, void* d_ws, size_t ws_size,
                              hipStream_t stream)
{
    const float* x       = (const float*)d_in[0];
    const int*   action  = (const int*)d_in[1];
    const float* mems    = (const float*)d_in[4];
    const float* act_emb = (const float*)d_in[5];
    const float* stem_w1 = (const float*)d_in[6];
    const float* sln1g   = (const float*)d_in[7];
    const float* sln1b   = (const float*)d_in[8];
    const float* stem_w2 = (const float*)d_in[9];
    const float* sln2g   = (const float*)d_in[10];
    const float* sln2b   = (const float*)d_in[11];
    const float* lnfg    = (const float*)d_in[12];
    const float* lnfb    = (const float*)d_in[13];
    const float* ub      = (const float*)d_in[14];
    const float* vb      = (const float*)d_in[15];
    const float* Wqkv    = (const float*)d_in[16];
    const float* Wr      = (const float*)d_in[17];
    const float* Wo      = (const float*)d_in[18];
    const float* ln1g    = (const float*)d_in[19];
    const float* ln1b    = (const float*)d_in[20];
    const float* W1      = (const float*)d_in[21];
    const float* b1      = (const float*)d_in[22];
    const float* W2      = (const float*)d_in[23];
    const float* b2      = (const float*)d_in[24];
    const float* ln2g    = (const float*)d_in[25];
    const float* ln2b    = (const float*)d_in[26];
    float* out = (float*)d_out;

    // ---- workspace layout (bytes) ----
    char* W = (char*)d_ws;
    float*  cur32 = (float*) (W + 0);           // 16 MB split-K z1 partial scratch
    float*  g32   = (float*) (W + 16777216);    // 16 MB f32 scratch / sk z0 partial
    ushort* curb  = (ushort*)(W + 33554432);    //  8 MB cur bf16 (residual stream)
    ushort* h1b   = (ushort*)(W + 41943040);    //  8 MB h1/ao bf16
    ushort* qb    = (ushort*)(W + 50331648);    //  8 MB q bf16 [8192][512]
    ushort* kvb   = (ushort*)(W + 58720256);    // 32 MB kv bf16 [16384][1024]
    ushort* peb   = (ushort*)(W + 92798976);    // 512 KB
    ushort* wts   = (ushort*)(W + 93323264);    // 27 MB transposed bf16 weights
    ushort* rbuf4 = (ushort*)(W + 121700352);   //  2 MB [4][512][512] r per layer
    ushort* xcatb = kvb;                        // stem alias (dead before kv use)
    ushort* ff1b  = kvb;                        // FF1 alias (kv dead post-attn)
    float*  wopart = (float*)kvb;               // Wo split-K z1 partial (post-attn)
    ushort* w1t    = wts;                       // [512][576]
    ushort* w2t    = wts + 294912;              // [512][512]
    ushort* wqkvT  = wts + 557056;              // [4][1536][512]
    ushort* wrT    = wts + 3702784;             // [4][512][512]
    ushort* woT    = wts + 4751360;             // [4][512][512]
    ushort* w1T    = wts + 5799936;             // [4][2048][512]
    ushort* w2T    = wts + 9994240;             // [4][512][2048]

    dim3 blk(256);
    // ---- merged prologue: posemb + xcat + 64x64 transposes ----
    const int wt_blocks = 72 + 64 + 768 + 256 + 256 + 1024 + 1024;    // 3464
    const int pro_blocks = 128 + 2304 + wt_blocks;                     // 5896
    wtrans_all<<<pro_blocks, blk, 0, stream>>>(
        stem_w1, stem_w2, Wqkv, Wr, Wo, W1, W2,
        w1t, w2t, wqkvT, wrT, woT, w1T, w2T,
        peb, x, action, act_emb, xcatb);

    gemm_bf<false, false, false><<<dim3(4, 64), blk, 0, stream>>>(xcatb, 576, w1t, 576, nullptr, g32, 512, 8192, 512, 576);
    ln_k<0, false><<<2048, blk, 0, stream>>>(g32, nullptr, nullptr, sln1g, sln1b, nullptr, curb, 1e-5f, 1);
    // stem GEMM2 split-K (2 blocks/CU): z0 -> g32, z1 -> cur32
    gemm_sk<false><<<dim3(4, 64, 2), blk, 0, stream>>>(curb, 512, w2t, 512, nullptr, g32, cur32, 512, 256);
    ln_stem2<<<2048, blk, 0, stream>>>(g32, cur32, sln2g, sln2b, lnfg, lnfb, curb);

    for (int l = 0; l < 4; ++l) {
        const ushort* wqkvT_l = wqkvT + (size_t)l * 786432;
        const float* memsf = mems + (size_t)l * 4194304;   // [8192][512] f32
        // merged q|kv(cur) + kv(mems, direct f32) (+r4 tiles when l==0)
        if (l == 0)
            gemm_qkv2<<<dim3(21, 64), blk, 0, stream>>>(curb, memsf, wqkvT_l, qb, kvb, peb, wrT, rbuf4);
        else
            gemm_qkv2<<<dim3(20, 64), blk, 0, stream>>>(curb, memsf, wqkvT_l, qb, kvb, peb, wrT, rbuf4);
        attn_mfma<<<512, dim3(512), 0, stream>>>(qb, kvb, rbuf4 + (size_t)l * 262144, ub, vb, h1b);
        // Wo split-K: z0 -> g32, z1 -> wopart (kvb region, dead post-attn)
        gemm_sk<false><<<dim3(4, 64, 2), blk, 0, stream>>>(h1b, 512, woT + (size_t)l * 262144, 512, nullptr, g32, wopart, 512, 256);
        // h1 = LN(g32 + wopart + residual curb[bf16])
        ln_k<3, false><<<2048, blk, 0, stream>>>(g32, wopart, curb, ln1g + l * 512, ln1b + l * 512, nullptr, h1b, 1e-5f, 0);
        gemm_bf<true, true, true><<<dim3(16, 64), blk, 0, stream>>>(h1b, 512, w1T + (size_t)l * 1048576, 512, b1 + l * 2048, ff1b, 2048, 8192, 2048, 512);
        // FF2 split-K: z0 -> g32 (+bias), z1 -> cur32 (f32 scratch)
        gemm_sk<true><<<dim3(4, 64, 2), blk, 0, stream>>>(ff1b, 2048, w2T + (size_t)l * 1048576, 2048, b2 + l * 512, g32, cur32, 512, 1024);
        if (l == 3)
            ln_k<3, true><<<2048, blk, 0, stream>>>(g32, cur32, h1b, ln2g + l * 512, ln2b + l * 512, out, nullptr, 1e-5f, 0);
        else
            ln_k<3, false><<<2048, blk, 0, stream>>>(g32, cur32, h1b, ln2g + l * 512, ln2b + l * 512, nullptr, curb, 1e-5f, 0);
    }
}

// Round 25
// 741.570 us; speedup vs baseline: 1.0342x; 1.0342x over previous
//
#include <hip/hip_runtime.h>

// TransformerXL forward, MI355X. Round 25: revert r24's direct-f32 qkv2
// staging (reg-staging exposed VMEM latency synchronously: qkv2 40->58 us,
// net +24). Back to r23 structure (743 us): conv pre-pass + gload16 bf16
// staging everywhere. One micro-fix: conv segment widened to 16 elem/thread
// (8192->4096 blocks). L=256, KLEN=512, B=32, E=512, H=8, D=64, FF=2048, NL=4.

typedef __attribute__((ext_vector_type(8))) short bf8_t;    // 8 bf16 in 4 VGPRs
typedef __attribute__((ext_vector_type(4))) float f4_t;
typedef __attribute__((ext_vector_type(16))) float fx16;    // 32x32 accum

__device__ __forceinline__ ushort f2bf(float f) {           // RNE f32->bf16
    uint u = __float_as_uint(f);
    u += 0x7FFFu + ((u >> 16) & 1u);
    return (ushort)(u >> 16);
}
__device__ __forceinline__ float b2f(ushort h) {
    return __uint_as_float(((uint)h) << 16);
}
__device__ __forceinline__ void gload16(const void* g, void* l) {
    __builtin_amdgcn_global_load_lds((const __attribute__((address_space(1))) void*)g,
                                     (__attribute__((address_space(3))) void*)l, 16, 0, 0);
}
// XCD-aware bijective remap (T1): XCD k gets a contiguous chunk of tiles.
__device__ __forceinline__ void xcd_tiles(int& mt, int& nt) {
    const int gx = gridDim.x;
    const int flat = (int)blockIdx.y * gx + (int)blockIdx.x;
    const int q = (gx * gridDim.y) >> 3;
    const int swz = (flat & 7) * q + (flat >> 3);
    nt = swz % gx;
    mt = swz / gx;
}

// ---------------- shared 32x32x16 MFMA core for one BK=64 step -------------
__device__ __forceinline__ void mma32_step(const ushort* __restrict__ As,
                                           const ushort* __restrict__ Bs,
                                           int rowA0, int colB0,
                                           int l31, int hi, fx16 acc[2][2])
{
#pragma unroll
    for (int kk = 0; kk < 4; ++kk) {
        bf8_t av[2], bv[2];
#pragma unroll
        for (int i = 0; i < 2; ++i) {
            const int row = rowA0 + i * 32 + l31;
            const int ch = (kk * 2 + hi) ^ (row & 7);
            av[i] = *(const bf8_t*)(As + row * 64 + ch * 8);
        }
#pragma unroll
        for (int j = 0; j < 2; ++j) {
            const int row = colB0 + j * 32 + l31;
            const int ch = (kk * 2 + hi) ^ (row & 7);
            bv[j] = *(const bf8_t*)(Bs + row * 64 + ch * 8);
        }
#pragma unroll
        for (int i = 0; i < 2; ++i)
#pragma unroll
            for (int j = 0; j < 2; ++j)
                acc[i][j] = __builtin_amdgcn_mfma_f32_32x32x16_bf16(av[i], bv[j], acc[i][j], 0, 0, 0);
    }
}

// ------------------------------------------------------------ MFMA GEMM bf16
template<bool BIAS, bool RELU, bool OUTBF>
__global__ __launch_bounds__(256)
void gemm_bf(const ushort* __restrict__ A, int lda,
             const ushort* __restrict__ Bt, int ldb,
             const float* __restrict__ bias,
             void* __restrict__ Cp, int ldc,
             int M, int N, int K)
{
    __shared__ __align__(16) ushort sh[17408];   // staging 32KB / epi [128][136]
    ushort* As = sh;
    ushort* Bs = sh + 8192;
    const int t = threadIdx.x;
    const int w = t >> 6, lane = t & 63;
    const int wr = w >> 1, wc = w & 1;
    const int l31 = lane & 31, hi = lane >> 5;
    int mt, nt; xcd_tiles(mt, nt);
    const int m0 = mt * 128, n0 = nt * 128;

    const int srow = w * 8 + (lane >> 3);
    const int gchunk = (lane & 7) ^ (srow & 7);
    const ushort* Ag = A + (size_t)(m0 + srow) * lda + gchunk * 8;
    const ushort* Bg = Bt + (size_t)(n0 + srow) * ldb + gchunk * 8;
    ushort* Asw = As + w * 512;
    ushort* Bsw = Bs + w * 512;

    fx16 acc[2][2];
#pragma unroll
    for (int i = 0; i < 2; ++i)
#pragma unroll
        for (int j = 0; j < 2; ++j)
#pragma unroll
            for (int r = 0; r < 16; ++r) acc[i][j][r] = 0.f;

    for (int k0 = 0; k0 < K; k0 += 64) {
#pragma unroll
        for (int c = 0; c < 4; ++c) {
            gload16(Ag + (size_t)c * 32 * lda, Asw + c * 2048);
            gload16(Bg + (size_t)c * 32 * ldb, Bsw + c * 2048);
        }
        Ag += 64; Bg += 64;
        __syncthreads();
        mma32_step(As, Bs, wr * 64, wc * 64, l31, hi, acc);
        __syncthreads();
    }
    const int crow0 = wr * 64, ccol0 = wc * 64;
    if (OUTBF) {
        ushort* Cs = sh;   // [128][136]
#pragma unroll
        for (int i = 0; i < 2; ++i)
#pragma unroll
            for (int j = 0; j < 2; ++j) {
                const int colb = ccol0 + j * 32 + l31;
                float bb = BIAS ? bias[n0 + colb] : 0.f;
                fx16 v = acc[i][j];
#pragma unroll
                for (int r = 0; r < 16; ++r) {
                    float o = v[r] + bb;
                    if (RELU) o = fmaxf(o, 0.f);
                    const int rw = crow0 + i * 32 + (r & 3) + 8 * (r >> 2) + 4 * hi;
                    Cs[rw * 136 + colb] = f2bf(o);
                }
            }
        __syncthreads();
        const int orow = t >> 1, oc0 = (t & 1) * 64;
        ushort* dst = (ushort*)Cp + (size_t)(m0 + orow) * ldc + n0 + oc0;
#pragma unroll
        for (int u = 0; u < 8; ++u)
            *(bf8_t*)(dst + u * 8) = *(const bf8_t*)(Cs + orow * 136 + oc0 + u * 8);
    } else {
        float* C = (float*)Cp;
#pragma unroll
        for (int i = 0; i < 2; ++i)
#pragma unroll
            for (int j = 0; j < 2; ++j) {
                const int colb = n0 + ccol0 + j * 32 + l31;
                float bb = BIAS ? bias[colb] : 0.f;
                fx16 v = acc[i][j];
#pragma unroll
                for (int r = 0; r < 16; ++r) {
                    float o = v[r] + bb;
                    if (RELU) o = fmaxf(o, 0.f);
                    const int rw = crow0 + i * 32 + (r & 3) + 8 * (r >> 2) + 4 * hi;
                    C[(size_t)(m0 + rw) * ldc + colb] = o;
                }
            }
    }
}

// --------- merged q|kv(cur) + kv(mems) GEMM (+layer-0: r = pos_emb @ Wr) ---
// grid (20,64) for l>0; (21,64) for l==0 where nt==20 routes the 64 r4 tiles
// (rid=mt: z=rid>>4, rm=(rid>>2)&3, rn=rid&3). 21*64=1344 % 8 == 0 (bijective).
__global__ __launch_bounds__(256)
void gemm_qkv2(const ushort* __restrict__ Acur, const ushort* __restrict__ Amem,
               const ushort* __restrict__ wqkvT_l,
               ushort* __restrict__ qout, ushort* __restrict__ kvout,
               const ushort* __restrict__ peA, const ushort* __restrict__ wrTall,
               ushort* __restrict__ r4out)
{
    __shared__ __align__(16) ushort sh[17408];
    ushort* As = sh;
    ushort* Bs = sh + 8192;
    const int t = threadIdx.x;
    const int w = t >> 6, lane = t & 63;
    const int wr = w >> 1, wc = w & 1;
    const int l31 = lane & 31, hi = lane >> 5;
    int mt, nt; xcd_tiles(mt, nt);

    int m0;
    const ushort* A;
    const ushort* Bt;
    ushort* base; size_t ldc2;
    if (nt >= 20) {          // layer-0 extra column: r = pos_emb @ Wr[z]
        const int rid = mt;  // 0..63
        const int rz = rid >> 4, rm = (rid >> 2) & 3, rn = rid & 3;
        m0 = rm * 128;
        A = peA;
        Bt = wrTall + (size_t)rz * 262144 + (size_t)(rn * 128) * 512;
        base = r4out + (size_t)rz * 262144 + rn * 128;
        ldc2 = 512;
    } else if (nt < 12) {
        const int n0 = nt * 128;
        m0 = mt * 128;
        A = Acur;
        Bt = wqkvT_l + (size_t)n0 * 512;
        if (n0 < 512) { base = qout + n0; ldc2 = 512; }
        else          { base = kvout + (size_t)8192 * 1024 + (n0 - 512); ldc2 = 1024; }
    } else {
        const int n0 = (nt - 12) * 128;
        m0 = mt * 128;
        A = Amem;
        Bt = wqkvT_l + (size_t)(512 + n0) * 512;
        base = kvout + n0; ldc2 = 1024;
    }

    const int srow = w * 8 + (lane >> 3);
    const int gchunk = (lane & 7) ^ (srow & 7);
    const ushort* Ag = A + (size_t)(m0 + srow) * 512 + gchunk * 8;
    const ushort* Bg = Bt + (size_t)srow * 512 + gchunk * 8;
    ushort* Asw = As + w * 512;
    ushort* Bsw = Bs + w * 512;

    fx16 acc[2][2];
#pragma unroll
    for (int i = 0; i < 2; ++i)
#pragma unroll
        for (int j = 0; j < 2; ++j)
#pragma unroll
            for (int r = 0; r < 16; ++r) acc[i][j][r] = 0.f;

    for (int k0 = 0; k0 < 512; k0 += 64) {
#pragma unroll
        for (int c = 0; c < 4; ++c) {
            gload16(Ag + (size_t)c * 32 * 512, Asw + c * 2048);
            gload16(Bg + (size_t)c * 32 * 512, Bsw + c * 2048);
        }
        Ag += 64; Bg += 64;
        __syncthreads();
        mma32_step(As, Bs, wr * 64, wc * 64, l31, hi, acc);
        __syncthreads();
    }
    const int crow0 = wr * 64, ccol0 = wc * 64;
    ushort* Cs = sh;   // [128][136]
#pragma unroll
    for (int i = 0; i < 2; ++i)
#pragma unroll
        for (int j = 0; j < 2; ++j) {
            const int colb = ccol0 + j * 32 + l31;
            fx16 v = acc[i][j];
#pragma unroll
            for (int r = 0; r < 16; ++r) {
                const int rw = crow0 + i * 32 + (r & 3) + 8 * (r >> 2) + 4 * hi;
                Cs[rw * 136 + colb] = f2bf(v[r]);
            }
        }
    __syncthreads();
    const int orow = t >> 1, oc0 = (t & 1) * 64;
    ushort* dst = base + (size_t)(m0 + orow) * ldc2 + oc0;
#pragma unroll
    for (int u = 0; u < 8; ++u)
        *(bf8_t*)(dst + u * 8) = *(const bf8_t*)(Cs + orow * 136 + oc0 + u * 8);
}

// ------------------------------------------------ split-K GEMM (f32 partials)
template<bool BIAS>
__global__ __launch_bounds__(256)
void gemm_sk(const ushort* __restrict__ A, int lda,
             const ushort* __restrict__ Bt, int ldb,
             const float* __restrict__ bias,
             float* __restrict__ C0, float* __restrict__ C1, int ldc, int KH)
{
    __shared__ __align__(16) ushort sh[16384];
    ushort* As = sh;
    ushort* Bs = sh + 8192;
    const int t = threadIdx.x;
    const int w = t >> 6, lane = t & 63;
    const int wr = w >> 1, wc = w & 1;
    const int l31 = lane & 31, hi = lane >> 5;
    int mt, nt; xcd_tiles(mt, nt);
    const int m0 = mt * 128, n0 = nt * 128;
    const int z = blockIdx.z;
    A += (size_t)z * KH; Bt += (size_t)z * KH;
    float* C = z ? C1 : C0;

    const int srow = w * 8 + (lane >> 3);
    const int gchunk = (lane & 7) ^ (srow & 7);
    const ushort* Ag = A + (size_t)(m0 + srow) * lda + gchunk * 8;
    const ushort* Bg = Bt + (size_t)(n0 + srow) * ldb + gchunk * 8;
    ushort* Asw = As + w * 512;
    ushort* Bsw = Bs + w * 512;

    fx16 acc[2][2];
#pragma unroll
    for (int i = 0; i < 2; ++i)
#pragma unroll
        for (int j = 0; j < 2; ++j)
#pragma unroll
            for (int r = 0; r < 16; ++r) acc[i][j][r] = 0.f;

    for (int k0 = 0; k0 < KH; k0 += 64) {
#pragma unroll
        for (int c = 0; c < 4; ++c) {
            gload16(Ag + (size_t)c * 32 * lda, Asw + c * 2048);
            gload16(Bg + (size_t)c * 32 * ldb, Bsw + c * 2048);
        }
        Ag += 64; Bg += 64;
        __syncthreads();
        mma32_step(As, Bs, wr * 64, wc * 64, l31, hi, acc);
        __syncthreads();
    }
    const int crow0 = wr * 64, ccol0 = wc * 64;
#pragma unroll
    for (int i = 0; i < 2; ++i)
#pragma unroll
        for (int j = 0; j < 2; ++j) {
            const int colb = n0 + ccol0 + j * 32 + l31;
            float bb = (BIAS && z == 0) ? bias[colb] : 0.f;
            fx16 v = acc[i][j];
#pragma unroll
            for (int r = 0; r < 16; ++r) {
                const int rw = crow0 + i * 32 + (r & 3) + 8 * (r >> 2) + 4 * hi;
                C[(size_t)(m0 + rw) * ldc + colb] = v[r] + bb;
            }
        }
}

// ---------------------------------------------------------------- LayerNorm
// RMODE: 0 X; 3 X+X2+Rbf16. TROUT: f32 out transposed to [B,L].
template<int RMODE, bool TROUT>
__global__ __launch_bounds__(256)
void ln_k(const float* __restrict__ X, const float* __restrict__ X2,
          const void* __restrict__ Rp,
          const float* __restrict__ g, const float* __restrict__ bt,
          float* __restrict__ Yf, ushort* __restrict__ Yb,
          float eps, int do_relu)
{
    const int row  = blockIdx.x * 4 + (threadIdx.x >> 6);
    const int lane = threadIdx.x & 63;
    const float* xp = X + (size_t)row * 512 + lane * 8;
    float4 x0 = *(const float4*)xp, x1 = *(const float4*)(xp + 4);
    float v[8] = {x0.x, x0.y, x0.z, x0.w, x1.x, x1.y, x1.z, x1.w};
    if (RMODE == 3) {
        const float* p2 = X2 + (size_t)row * 512 + lane * 8;
        float4 a0 = *(const float4*)p2, a1 = *(const float4*)(p2 + 4);
        v[0] += a0.x; v[1] += a0.y; v[2] += a0.z; v[3] += a0.w;
        v[4] += a1.x; v[5] += a1.y; v[6] += a1.z; v[7] += a1.w;
        const ushort* rp = (const ushort*)Rp + (size_t)row * 512 + lane * 8;
        ushort4 r0 = *(const ushort4*)rp, r1 = *(const ushort4*)(rp + 4);
        v[0] += b2f(r0.x); v[1] += b2f(r0.y); v[2] += b2f(r0.z); v[3] += b2f(r0.w);
        v[4] += b2f(r1.x); v[5] += b2f(r1.y); v[6] += b2f(r1.z); v[7] += b2f(r1.w);
    }
    float s = 0.f;
#pragma unroll
    for (int i = 0; i < 8; ++i) s += v[i];
#pragma unroll
    for (int m = 1; m < 64; m <<= 1) s += __shfl_xor(s, m);
    float mean = s * (1.f / 512.f);
    float q = 0.f;
#pragma unroll
    for (int i = 0; i < 8; ++i) { float d = v[i] - mean; q = fmaf(d, d, q); }
#pragma unroll
    for (int m = 1; m < 64; m <<= 1) q += __shfl_xor(q, m);
    float rstd = rsqrtf(q * (1.f / 512.f) + eps);
    float4 g0 = *(const float4*)(g + lane * 8), g1 = *(const float4*)(g + lane * 8 + 4);
    float4 c0 = *(const float4*)(bt + lane * 8), c1 = *(const float4*)(bt + lane * 8 + 4);
    float gv[8] = {g0.x, g0.y, g0.z, g0.w, g1.x, g1.y, g1.z, g1.w};
    float bv[8] = {c0.x, c0.y, c0.z, c0.w, c1.x, c1.y, c1.z, c1.w};
    float o[8];
#pragma unroll
    for (int i = 0; i < 8; ++i) {
        o[i] = (v[i] - mean) * rstd * gv[i] + bv[i];
        if (do_relu) o[i] = fmaxf(o[i], 0.f);
    }
    if (Yf) {
        float* yp;
        if (TROUT) {
            const int bq = row & 31, lq = row >> 5;
            yp = Yf + ((size_t)bq * 256 + lq) * 512 + lane * 8;
        } else {
            yp = Yf + (size_t)row * 512 + lane * 8;
        }
        *(float4*)yp       = make_float4(o[0], o[1], o[2], o[3]);
        *(float4*)(yp + 4) = make_float4(o[4], o[5], o[6], o[7]);
    }
    if (Yb) {
        ushort* yp = Yb + (size_t)row * 512 + lane * 8;
        ushort4 w0, w1;
        w0.x = f2bf(o[0]); w0.y = f2bf(o[1]); w0.z = f2bf(o[2]); w0.w = f2bf(o[3]);
        w1.x = f2bf(o[4]); w1.y = f2bf(o[5]); w1.z = f2bf(o[6]); w1.w = f2bf(o[7]);
        *(ushort4*)yp       = w0;
        *(ushort4*)(yp + 4) = w1;
    }
}

// ------------------ fused stem double LN (ln2 -> lnf), X = X1 + X2 partials
__global__ __launch_bounds__(256)
void ln_stem2(const float* __restrict__ X, const float* __restrict__ X2,
              const float* __restrict__ g1, const float* __restrict__ b1,
              const float* __restrict__ g2, const float* __restrict__ b2,
              ushort* __restrict__ Yb)
{
    const int row  = blockIdx.x * 4 + (threadIdx.x >> 6);
    const int lane = threadIdx.x & 63;
    const float* xp = X + (size_t)row * 512 + lane * 8;
    const float* ap = X2 + (size_t)row * 512 + lane * 8;
    float4 x0 = *(const float4*)xp, x1 = *(const float4*)(xp + 4);
    float4 a0 = *(const float4*)ap, a1 = *(const float4*)(ap + 4);
    float v[8] = {x0.x + a0.x, x0.y + a0.y, x0.z + a0.z, x0.w + a0.w,
                  x1.x + a1.x, x1.y + a1.y, x1.z + a1.z, x1.w + a1.w};
    float s = 0.f;
#pragma unroll
    for (int i = 0; i < 8; ++i) s += v[i];
#pragma unroll
    for (int m = 1; m < 64; m <<= 1) s += __shfl_xor(s, m);
    float mean = s * (1.f / 512.f);
    float q = 0.f;
#pragma unroll
    for (int i = 0; i < 8; ++i) { float d = v[i] - mean; q = fmaf(d, d, q); }
#pragma unroll
    for (int m = 1; m < 64; m <<= 1) q += __shfl_xor(q, m);
    float rstd = rsqrtf(q * (1.f / 512.f) + 1e-5f);
#pragma unroll
    for (int i = 0; i < 8; ++i)
        v[i] = (v[i] - mean) * rstd * g1[lane * 8 + i] + b1[lane * 8 + i];
    s = 0.f;
#pragma unroll
    for (int i = 0; i < 8; ++i) s += v[i];
#pragma unroll
    for (int m = 1; m < 64; m <<= 1) s += __shfl_xor(s, m);
    mean = s * (1.f / 512.f);
    q = 0.f;
#pragma unroll
    for (int i = 0; i < 8; ++i) { float d = v[i] - mean; q = fmaf(d, d, q); }
#pragma unroll
    for (int m = 1; m < 64; m <<= 1) q += __shfl_xor(q, m);
    rstd = rsqrtf(q * (1.f / 512.f) + 1e-6f);
    float o[8];
#pragma unroll
    for (int i = 0; i < 8; ++i)
        o[i] = (v[i] - mean) * rstd * g2[lane * 8 + i] + b2[lane * 8 + i];
    ushort* yb = Yb + (size_t)row * 512 + lane * 8;
    ushort4 w0, w1;
    w0.x = f2bf(o[0]); w0.y = f2bf(o[1]); w0.z = f2bf(o[2]); w0.w = f2bf(o[3]);
    w1.x = f2bf(o[4]); w1.y = f2bf(o[5]); w1.z = f2bf(o[6]); w1.w = f2bf(o[7]);
    *(ushort4*)yb       = w0;
    *(ushort4*)(yb + 4) = w1;
}

// ---------------- merged prologue: conv + posemb + xcat + all transposes ---
// Flat grid routing: [4096 conv (opt, 16 e/thr)] [128 posemb] [2304 xcat]
// [3464 wt]. All segments >= 8 elem/thread with 16B stores.
__global__ __launch_bounds__(256)
void wtrans_all(const float* __restrict__ sw1, const float* __restrict__ sw2,
                const float* __restrict__ Wqkv, const float* __restrict__ Wr,
                const float* __restrict__ Wo, const float* __restrict__ W1w,
                const float* __restrict__ W2w,
                ushort* __restrict__ w1t, ushort* __restrict__ w2t,
                ushort* __restrict__ wqkvT, ushort* __restrict__ wrT,
                ushort* __restrict__ woT, ushort* __restrict__ w1T,
                ushort* __restrict__ w2T,
                const float* __restrict__ mems, ushort* __restrict__ memsb4,
                int do_conv,
                ushort* __restrict__ pe,
                const float* __restrict__ x, const int* __restrict__ action,
                const float* __restrict__ act_emb, ushort* __restrict__ xcat)
{
    int id = (int)blockIdx.x;
    if (do_conv) {
        if (id < 4096) {    // batched mems -> bf16 (all 4 layers), 16 elem/thr
            int i = (id * 256 + threadIdx.x) * 16;
#pragma unroll
            for (int hh = 0; hh < 2; ++hh) {
                float4 v0 = *(const float4*)(mems + i + hh * 8);
                float4 v1 = *(const float4*)(mems + i + hh * 8 + 4);
                bf8_t o8;
                o8[0] = (short)f2bf(v0.x); o8[1] = (short)f2bf(v0.y);
                o8[2] = (short)f2bf(v0.z); o8[3] = (short)f2bf(v0.w);
                o8[4] = (short)f2bf(v1.x); o8[5] = (short)f2bf(v1.y);
                o8[6] = (short)f2bf(v1.z); o8[7] = (short)f2bf(v1.w);
                *(bf8_t*)(memsb4 + i + hh * 8) = o8;
            }
            return;
        }
        id -= 4096;
    }
    if (id < 128) {         // sinusoidal pos embedding, 8 c/thread
        int v = id * 256 + threadIdx.x;            // 32768 threads
        int j = v >> 6, c0 = (v & 63) * 8;
        float pf = (float)(511 - j);
        bf8_t o8;
#pragma unroll
        for (int e = 0; e < 8; ++e) {
            int c = c0 + e;
            int i2 = (c < 256) ? c : c - 256;
            float inv = expf(-(float)i2 * 0.03597789207803197f);
            float ang = pf * inv;
            o8[e] = (short)f2bf((c < 256) ? sinf(ang) : cosf(ang));
        }
        *(bf8_t*)(pe + (size_t)j * 512 + c0) = o8;
        return;
    }
    id -= 128;
    if (id < 2304) {        // stem concat [x | act], 8 e/thread
        int v = id * 256 + threadIdx.x;            // 8192*72 groups
        int n = v / 72, eg = v - n * 72;
        int e0 = eg * 8;
        int l = n >> 5, b = n & 31;
        float4 v0, v1;
        if (e0 < 512) {
            const float* src = x + ((size_t)b * 256 + l) * 512 + e0;
            v0 = *(const float4*)src;
            v1 = *(const float4*)(src + 4);
        } else {
            const float* src = act_emb + (size_t)action[b * 32 + (l >> 3)] * 64 + (e0 - 512);
            v0 = *(const float4*)src;
            v1 = *(const float4*)(src + 4);
        }
        bf8_t o8;
        o8[0] = (short)f2bf(v0.x); o8[1] = (short)f2bf(v0.y);
        o8[2] = (short)f2bf(v0.z); o8[3] = (short)f2bf(v0.w);
        o8[4] = (short)f2bf(v1.x); o8[5] = (short)f2bf(v1.y);
        o8[6] = (short)f2bf(v1.z); o8[7] = (short)f2bf(v1.w);
        *(bf8_t*)(xcat + (size_t)n * 576 + e0) = o8;
        return;
    }
    id -= 2304;
    // ---- 64x64 transpose tiles ----
    const float* in; ushort* out; int K, N, nx, bz = 0;
    if (id < 72) { in = sw1; out = w1t; K = 576; N = 512; nx = 8; }
    else if ((id -= 72) < 64) { in = sw2; out = w2t; K = 512; N = 512; nx = 8; }
    else if ((id -= 64) < 768) { in = Wqkv; out = wqkvT; K = 512; N = 1536; nx = 24; bz = id / 192; id -= bz * 192; }
    else if ((id -= 768) < 256) { in = Wr; out = wrT; K = 512; N = 512; nx = 8; bz = id / 64; id -= bz * 64; }
    else if ((id -= 256) < 256) { in = Wo; out = woT; K = 512; N = 512; nx = 8; bz = id / 64; id -= bz * 64; }
    else if ((id -= 256) < 1024) { in = W1w; out = w1T; K = 512; N = 2048; nx = 32; bz = id / 256; id -= bz * 256; }
    else { id -= 1024; in = W2w; out = w2T; K = 2048; N = 512; nx = 8; bz = id / 256; id -= bz * 256; }
    const int bx = id % nx, by = id / nx;
    __shared__ float tl[64][65];
    const size_t bo = (size_t)bz * K * N;
    const float* inp = in + bo;
    ushort* outp = out + bo;
    const int k0 = by * 64, n0 = bx * 64;
    const int tx4 = (threadIdx.x & 15) * 4, ty = threadIdx.x >> 4;   // 16x16
#pragma unroll
    for (int p2 = 0; p2 < 4; ++p2) {
        const int row = p2 * 16 + ty;
        float4 v = *(const float4*)(inp + (size_t)(k0 + row) * N + n0 + tx4);
        tl[row][tx4] = v.x; tl[row][tx4 + 1] = v.y;
        tl[row][tx4 + 2] = v.z; tl[row][tx4 + 3] = v.w;
    }
    __syncthreads();
    const int nn = threadIdx.x >> 3, kk = (threadIdx.x & 7) * 8;     // 32 n/pass
#pragma unroll
    for (int p2 = 0; p2 < 2; ++p2) {
        const int n = p2 * 32 + nn;
        bf8_t o8;
#pragma unroll
        for (int e = 0; e < 8; ++e) o8[e] = (short)f2bf(tl[kk + e][n]);
        *(bf8_t*)(outp + (size_t)(n0 + n) * K + k0 + kk) = o8;
    }
}

__global__ void convk(const float* __restrict__ in, ushort* __restrict__ out)
{
    int i = (blockIdx.x * 256 + threadIdx.x) * 4;
    float4 v = *(const float4*)(in + i);
    ushort4 o;
    o.x = f2bf(v.x); o.y = f2bf(v.y); o.z = f2bf(v.z); o.w = f2bf(v.w);
    *(ushort4*)(out + i) = o;
}

// --------------------------------------------------- MFMA flash attention
// r23 kernel: XCD remap, Vs XOR-swizzle, Rs rolling band, T14 prefetch,
// T5 setprio, T13 defer-max, deferred softmax-sum + deferred max-reduce.
__global__ __launch_bounds__(512)
void attn_mfma(const ushort* __restrict__ q,    // [256*32][512]
               const ushort* __restrict__ kv,   // [512*32][1024]  k | v halves
               const ushort* __restrict__ rb,   // [512][512]
               const float* __restrict__ ub, const float* __restrict__ vb,
               ushort* __restrict__ ao)         // [256*32][512]
{
    __shared__ __align__(16) ushort Ks[64][72];     // K tile  [j][d]
    __shared__ __align__(16) ushort Vs[64][72];     // V^T tile [d][j], XOR-swz
    __shared__ __align__(16) ushort Rs[192][72];    // rolling r band (3 slabs)
    __shared__ __align__(16) ushort Ps[8][16][72];  // per-wave P / O bounce
    const int t = threadIdx.x;
    const int wv = t >> 6, lane = t & 63;
    const int lc = lane & 15, lr = lane >> 4;
    const int p = (int)blockIdx.x;
    const int b = (p & 7) * 4 + (p >> 7);
    const int hi2 = (p >> 3) & 15;
    const int h = hi2 >> 1, ihalf = hi2 & 1;
    const int i0 = ihalf << 7;
    const int iw = i0 + wv * 16;

    bf8_t au[2], aw[2];
#pragma unroll
    for (int kk = 0; kk < 2; ++kk) {
        const ushort* qp = q + ((size_t)(iw + lc) * 32 + b) * 512 + h * 64 + kk * 32 + lr * 8;
        bf8_t q8 = *(const bf8_t*)qp;
        const float* up = ub + h * 64 + kk * 32 + lr * 8;
        const float* vp = vb + h * 64 + kk * 32 + lr * 8;
#pragma unroll
        for (int e = 0; e < 8; ++e) {
            float qf = b2f((ushort)q8[e]);
            au[kk][e] = (short)f2bf(qf + up[e]);
            aw[kk][e] = (short)f2bf(qf + vp[e]);
        }
    }

    const int jl = t >> 3, d0 = (t & 7) * 8;
    const int vrow = ((t >> 3) & 7) * 8 + wv;
    const int vswz = ((((vrow >> 3) ^ (t & 7)) & 7) << 3) + (vrow & 7);

    f4_t o[4];
#pragma unroll
    for (int d = 0; d < 4; ++d) o[d] = (f4_t){0.f, 0.f, 0.f, 0.f};
    float mrun[4] = {-3.0e38f, -3.0e38f, -3.0e38f, -3.0e38f};
    float lrun[4] = {0.f, 0.f, 0.f, 0.f};   // per-lane PARTIAL (4 cols/lane)

    {
        *(bf8_t*)&Ks[jl][d0] = *(const bf8_t*)(kv + ((size_t)jl * 32 + b) * 1024 + h * 64 + d0);
        bf8_t vv = *(const bf8_t*)(kv + ((size_t)vrow * 32 + b) * 1024 + 512 + h * 64 + d0);
#pragma unroll
        for (int e = 0; e < 8; ++e) Vs[d0 + e][vswz] = (ushort)vv[e];
        const int rbase0 = 128 - i0;
#pragma unroll
        for (int p2 = 0; p2 < 3; ++p2) {
            const int jr = min(rbase0 + p2 * 64 + jl, 511);
            *(bf8_t*)&Rs[p2 * 64 + jl][d0] = *(const bf8_t*)(rb + (size_t)jr * 512 + h * 64 + d0);
        }
    }
    __syncthreads();

    const int njt = ihalf ? 8 : 6;
    for (int jt = 0; jt < njt; ++jt) {
        const int j0 = jt << 6;
        bf8_t pk, pv, pr;
        const bool pfq = (jt + 1 < njt);
        if (pfq) {
            const int j0n = j0 + 64;
            pk = *(const bf8_t*)(kv + ((size_t)(j0n + jl) * 32 + b) * 1024 + h * 64 + d0);
            pv = *(const bf8_t*)(kv + ((size_t)(j0n + vrow) * 32 + b) * 1024 + 512 + h * 64 + d0);
            const int jr = min(j0n - i0 + 256 + jl, 511);
            pr = *(const bf8_t*)(rb + (size_t)jr * 512 + h * 64 + d0);
        }
        if (j0 <= iw + 271) {
            f4_t acf[4], bdf[5];
#pragma unroll
            for (int jj = 0; jj < 4; ++jj) acf[jj] = (f4_t){0.f, 0.f, 0.f, 0.f};
#pragma unroll
            for (int fj = 0; fj < 5; ++fj) bdf[fj] = (f4_t){0.f, 0.f, 0.f, 0.f};
            __builtin_amdgcn_s_setprio(1);
#pragma unroll
            for (int jj = 0; jj < 4; ++jj)
#pragma unroll
                for (int kk = 0; kk < 2; ++kk) {
                    bf8_t kf = *(const bf8_t*)&Ks[jj * 16 + lc][kk * 32 + lr * 8];
                    acf[jj] = __builtin_amdgcn_mfma_f32_16x16x32_bf16(au[kk], kf, acf[jj], 0, 0, 0);
                }
            const int rboff = 112 - wv * 16;
#pragma unroll
            for (int fj = 0; fj < 5; ++fj) {
                const int lbase = rboff + fj * 16;
                const int prow = ((jt + (lbase >> 6)) % 3) * 64 + (lbase & 63) + lc;
#pragma unroll
                for (int kk = 0; kk < 2; ++kk) {
                    bf8_t rf = *(const bf8_t*)&Rs[prow][kk * 32 + lr * 8];
                    bdf[fj] = __builtin_amdgcn_mfma_f32_16x16x32_bf16(aw[kk], rf, bdf[fj], 0, 0, 0);
                }
            }
            __builtin_amdgcn_s_setprio(0);
            float pm[4][4];
            float mt2[4] = {-3.0e38f, -3.0e38f, -3.0e38f, -3.0e38f};
            const int jbase = j0 + lc - iw - 256;
#pragma unroll
            for (int rg = 0; rg < 4; ++rg) {
                const int il = lr * 4 + rg;
                const int srcl = (lane & 48) | ((lc + 15 - il) & 15);
                float shf[5];
#pragma unroll
                for (int fj = 0; fj < 5; ++fj) shf[fj] = __shfl(bdf[fj][rg], srcl, 64);
#pragma unroll
                for (int jj = 0; jj < 4; ++jj) {
                    float bd = (lc > il) ? shf[jj + 1] : shf[jj];
                    float s = (acf[jj][rg] + bd) * 0.125f;
                    if (jbase + jj * 16 > il) s = -1e30f;
                    pm[jj][rg] = s;
                    mt2[rg] = fmaxf(mt2[rg], s);
                }
            }
            // deferred max-reduce: per-lane partial check first; the 16-lane
            // reduce runs only when a rescale actually triggers (rare).
            const bool within = (mt2[0] <= mrun[0] + 8.f) & (mt2[1] <= mrun[1] + 8.f) &
                                (mt2[2] <= mrun[2] + 8.f) & (mt2[3] <= mrun[3] + 8.f);
            const bool skip_rescale = __all(within);
            float corr[4] = {1.f, 1.f, 1.f, 1.f};
            if (!skip_rescale) {
#pragma unroll
                for (int rg = 0; rg < 4; ++rg) {
#pragma unroll
                    for (int mm = 1; mm < 16; mm <<= 1)
                        mt2[rg] = fmaxf(mt2[rg], __shfl_xor(mt2[rg], mm, 64));
                    float mnew = fmaxf(mrun[rg], mt2[rg]);
                    corr[rg] = __expf(mrun[rg] - mnew);
                    mrun[rg] = mnew;
                }
            }
            float ps4[4] = {0.f, 0.f, 0.f, 0.f};
#pragma unroll
            for (int jj = 0; jj < 4; ++jj)
#pragma unroll
                for (int rg = 0; rg < 4; ++rg) {
                    float pp = __expf(pm[jj][rg] - mrun[rg]);
                    ps4[rg] += pp;
                    Ps[wv][lr * 4 + rg][jj * 16 + lc] = f2bf(pp);
                }
            // deferred: lrun stays a per-lane partial (corr is lane-uniform)
#pragma unroll
            for (int rg = 0; rg < 4; ++rg)
                lrun[rg] = lrun[rg] * corr[rg] + ps4[rg];
            if (!skip_rescale) {
                float c0 = __shfl(corr[0], (lc >> 2) << 4, 64);
                float c1 = __shfl(corr[1], (lc >> 2) << 4, 64);
                float c2 = __shfl(corr[2], (lc >> 2) << 4, 64);
                float c3 = __shfl(corr[3], (lc >> 2) << 4, 64);
                float myc = (lc & 2) ? ((lc & 1) ? c3 : c2) : ((lc & 1) ? c1 : c0);
#pragma unroll
                for (int db = 0; db < 4; ++db)
#pragma unroll
                    for (int rg = 0; rg < 4; ++rg) o[db][rg] *= myc;
            }
            __builtin_amdgcn_s_setprio(1);
#pragma unroll
            for (int kb = 0; kb < 2; ++kb) {
                bf8_t pf = *(const bf8_t*)&Ps[wv][lc][kb * 32 + lr * 8];
#pragma unroll
                for (int db = 0; db < 4; ++db) {
                    const int vr = db * 16 + lc;
                    bf8_t vf = *(const bf8_t*)&Vs[vr][((kb * 4 + lr) ^ ((vr >> 3) & 7)) * 8];
                    o[db] = __builtin_amdgcn_mfma_f32_16x16x32_bf16(vf, pf, o[db], 0, 0, 0);
                }
            }
            __builtin_amdgcn_s_setprio(0);
        }
        __syncthreads();
        if (pfq) {
            *(bf8_t*)&Ks[jl][d0] = pk;
#pragma unroll
            for (int e = 0; e < 8; ++e) Vs[d0 + e][vswz] = (ushort)pv[e];
            const int phys = (jt % 3) * 64 + jl;
            *(bf8_t*)&Rs[phys][d0] = pr;
        }
        __syncthreads();
    }
    // ---- epilogue: single 16-lane sum reduce, then scale + store ----
    float i4[4];
#pragma unroll
    for (int rg = 0; rg < 4; ++rg) {
#pragma unroll
        for (int mm = 1; mm < 16; mm <<= 1)
            lrun[rg] += __shfl_xor(lrun[rg], mm, 64);
        i4[rg] = 1.f / lrun[rg];
    }
    float s0 = __shfl(i4[0], (lc >> 2) << 4, 64);
    float s1 = __shfl(i4[1], (lc >> 2) << 4, 64);
    float s2 = __shfl(i4[2], (lc >> 2) << 4, 64);
    float s3 = __shfl(i4[3], (lc >> 2) << 4, 64);
    float myi = (lc & 2) ? ((lc & 1) ? s3 : s2) : ((lc & 1) ? s1 : s0);
#pragma unroll
    for (int db = 0; db < 4; ++db)
#pragma unroll
        for (int rg = 0; rg < 4; ++rg)
            Ps[wv][lc][db * 16 + lr * 4 + rg] = f2bf(o[db][rg] * myi);
    const int il2 = lane >> 2, dsg = (lane & 3) << 4;
    bf8_t e0 = *(const bf8_t*)&Ps[wv][il2][dsg];
    bf8_t e1 = *(const bf8_t*)&Ps[wv][il2][dsg + 8];
    ushort* dst = ao + ((size_t)(iw + il2) * 32 + b) * 512 + h * 64 + dsg;
    *(bf8_t*)dst = e0;
    *(bf8_t*)(dst + 8) = e1;
}

// ---------------------------------------------------------------------------
extern "C" void kernel_launch(void* const* d_in, const int* in_sizes, int n_in,
                              void* d_out, int out_size, void* d_ws, size_t ws_size,
                              hipStream_t stream)
{
    const float* x       = (const float*)d_in[0];
    const int*   action  = (const int*)d_in[1];
    const float* mems    = (const float*)d_in[4];
    const float* act_emb = (const float*)d_in[5];
    const float* stem_w1 = (const float*)d_in[6];
    const float* sln1g   = (const float*)d_in[7];
    const float* sln1b   = (const float*)d_in[8];
    const float* stem_w2 = (const float*)d_in[9];
    const float* sln2g   = (const float*)d_in[10];
    const float* sln2b   = (const float*)d_in[11];
    const float* lnfg    = (const float*)d_in[12];
    const float* lnfb    = (const float*)d_in[13];
    const float* ub      = (const float*)d_in[14];
    const float* vb      = (const float*)d_in[15];
    const float* Wqkv    = (const float*)d_in[16];
    const float* Wr      = (const float*)d_in[17];
    const float* Wo      = (const float*)d_in[18];
    const float* ln1g    = (const float*)d_in[19];
    const float* ln1b    = (const float*)d_in[20];
    const float* W1      = (const float*)d_in[21];
    const float* b1      = (const float*)d_in[22];
    const float* W2      = (const float*)d_in[23];
    const float* b2      = (const float*)d_in[24];
    const float* ln2g    = (const float*)d_in[25];
    const float* ln2b    = (const float*)d_in[26];
    float* out = (float*)d_out;

    // ---- workspace layout (bytes) ----
    char* W = (char*)d_ws;
    float*  cur32 = (float*) (W + 0);           // 16 MB split-K z1 partial scratch
    float*  g32   = (float*) (W + 16777216);    // 16 MB f32 scratch / sk z0 partial
    ushort* curb  = (ushort*)(W + 33554432);    //  8 MB cur bf16 (residual stream)
    ushort* h1b   = (ushort*)(W + 41943040);    //  8 MB h1/ao bf16
    ushort* qb    = (ushort*)(W + 50331648);    //  8 MB q bf16 [8192][512]
    ushort* kvb   = (ushort*)(W + 58720256);    // 32 MB kv bf16 [16384][1024]
    ushort* peb   = (ushort*)(W + 92798976);    // 512 KB
    ushort* wts   = (ushort*)(W + 93323264);    // 27 MB transposed bf16 weights
    ushort* rbuf4 = (ushort*)(W + 121700352);   //  2 MB [4][512][512] r per layer
    ushort* memsb4 = (ushort*)(W + 123797504);  // 32 MB [4][8192][1024] (optional)
    const bool big_ws = ws_size >= (size_t)123797504 + 33554432;
    ushort* xcatb = kvb;                        // stem alias (dead before kv use)
    ushort* ff1b  = kvb;                        // FF1 alias (kv dead post-attn)
    float*  wopart = (float*)kvb;               // Wo split-K z1 partial (post-attn)
    ushort* memsb = (ushort*)g32;               // per-layer fallback alias
    ushort* w1t    = wts;                       // [512][576]
    ushort* w2t    = wts + 294912;              // [512][512]
    ushort* wqkvT  = wts + 557056;              // [4][1536][512]
    ushort* wrT    = wts + 3702784;             // [4][512][512]
    ushort* woT    = wts + 4751360;             // [4][512][512]
    ushort* w1T    = wts + 5799936;             // [4][2048][512]
    ushort* w2T    = wts + 9994240;             // [4][512][2048]

    dim3 blk(256);
    // ---- merged prologue: conv(opt) + posemb + xcat + 64x64 transposes ----
    const int wt_blocks = 72 + 64 + 768 + 256 + 256 + 1024 + 1024;    // 3464
    const int pro_blocks = (big_ws ? 4096 : 0) + 128 + 2304 + wt_blocks;
    wtrans_all<<<pro_blocks, blk, 0, stream>>>(
        stem_w1, stem_w2, Wqkv, Wr, Wo, W1, W2,
        w1t, w2t, wqkvT, wrT, woT, w1T, w2T,
        mems, memsb4, big_ws ? 1 : 0,
        peb, x, action, act_emb, xcatb);

    gemm_bf<false, false, false><<<dim3(4, 64), blk, 0, stream>>>(xcatb, 576, w1t, 576, nullptr, g32, 512, 8192, 512, 576);
    ln_k<0, false><<<2048, blk, 0, stream>>>(g32, nullptr, nullptr, sln1g, sln1b, nullptr, curb, 1e-5f, 1);
    // stem GEMM2 split-K (2 blocks/CU): z0 -> g32, z1 -> cur32
    gemm_sk<false><<<dim3(4, 64, 2), blk, 0, stream>>>(curb, 512, w2t, 512, nullptr, g32, cur32, 512, 256);
    ln_stem2<<<2048, blk, 0, stream>>>(g32, cur32, sln2g, sln2b, lnfg, lnfb, curb);

    for (int l = 0; l < 4; ++l) {
        const ushort* wqkvT_l = wqkvT + (size_t)l * 786432;
        const ushort* mA;
        if (big_ws) {
            mA = memsb4 + (size_t)l * 4194304;
        } else {
            convk<<<4096, blk, 0, stream>>>(mems + (size_t)l * 4194304, memsb);
            mA = memsb;
        }
        // merged q|kv(cur) + kv(mems) (+r4 tiles when l==0 via 21st column)
        if (l == 0)
            gemm_qkv2<<<dim3(21, 64), blk, 0, stream>>>(curb, mA, wqkvT_l, qb, kvb, peb, wrT, rbuf4);
        else
            gemm_qkv2<<<dim3(20, 64), blk, 0, stream>>>(curb, mA, wqkvT_l, qb, kvb, peb, wrT, rbuf4);
        attn_mfma<<<512, dim3(512), 0, stream>>>(qb, kvb, rbuf4 + (size_t)l * 262144, ub, vb, h1b);
        // Wo split-K: z0 -> g32, z1 -> wopart (kvb region, dead post-attn)
        gemm_sk<false><<<dim3(4, 64, 2), blk, 0, stream>>>(h1b, 512, woT + (size_t)l * 262144, 512, nullptr, g32, wopart, 512, 256);
        // h1 = LN(g32 + wopart + residual curb[bf16])
        ln_k<3, false><<<2048, blk, 0, stream>>>(g32, wopart, curb, ln1g + l * 512, ln1b + l * 512, nullptr, h1b, 1e-5f, 0);
        gemm_bf<true, true, true><<<dim3(16, 64), blk, 0, stream>>>(h1b, 512, w1T + (size_t)l * 1048576, 512, b1 + l * 2048, ff1b, 2048, 8192, 2048, 512);
        // FF2 split-K: z0 -> g32 (+bias), z1 -> cur32 (f32 scratch)
        gemm_sk<true><<<dim3(4, 64, 2), blk, 0, stream>>>(ff1b, 2048, w2T + (size_t)l * 1048576, 2048, b2 + l * 512, g32, cur32, 512, 1024);
        if (l == 3)
            ln_k<3, true><<<2048, blk, 0, stream>>>(g32, cur32, h1b, ln2g + l * 512, ln2b + l * 512, out, nullptr, 1e-5f, 0);
        else
            ln_k<3, false><<<2048, blk, 0, stream>>>(g32, cur32, h1b, ln2g + l * 512, ln2b + l * 512, nullptr, curb, 1e-5f, 0);
    }
}